// Round 10
// baseline (4195.475 us; speedup 1.0000x reference)
//
#include <hip/hip_runtime.h>

#define T_LEN 200
#define HID   256
#define BATCH 1024
#define G3    768
#define ROWS  16      // slab tile rows (h0 slab, xp_gemm A-tile granularity)
#define RROWS 8       // batch rows per recurrent block
#define NBLK  128     // recurrent blocks = BATCH / RROWS
#define NTHREADS 512
#define WSZ   196608  // 768*256 elements per GRU weight matrix

typedef __bf16  bf16x8 __attribute__((ext_vector_type(8)));
typedef float   f32x4  __attribute__((ext_vector_type(4)));

__device__ __forceinline__ unsigned short f2bf(float f) {
  union { float f; unsigned int u; } c; c.f = f;
  unsigned int u = c.u;
  u += 0x7FFFu + ((u >> 16) & 1u);     // round-to-nearest-even
  return (unsigned short)(u >> 16);
}
__device__ __forceinline__ float bf2f(unsigned int u16v) {
  union { unsigned int u; float f; } c; c.u = u16v << 16; return c.f;
}
__device__ __forceinline__ float sigm(float x) { return 1.0f / (1.0f + __expf(-x)); }
__device__ __forceinline__ float tanh_f(float x) { return 1.0f - 2.0f / (__expf(2.0f * x) + 1.0f); }

__global__ void convert_weights(const float* __restrict__ a,
                                const float* __restrict__ b,
                                const float* __restrict__ c,
                                const float* __restrict__ d,
                                const float* __restrict__ e,
                                unsigned short* __restrict__ out) {
  int i = blockIdx.x * blockDim.x + threadIdx.x;
  const int total = 4 * WSZ + HID * HID;
  if (i >= total) return;
  float v;
  if      (i < 1 * WSZ) v = a[i];
  else if (i < 2 * WSZ) v = b[i - 1 * WSZ];
  else if (i < 3 * WSZ) v = c[i - 2 * WSZ];
  else if (i < 4 * WSZ) v = d[i - 3 * WSZ];
  else                  v = e[i - 4 * WSZ];
  out[i] = f2bf(v);
}

__device__ __forceinline__ bf16x8 lds_frag(const unsigned short* buf, int row, int k, int lq) {
  int chunk = (k << 2) + lq;
  int idx = row * HID + ((chunk ^ (row & 7)) << 3);
  return *reinterpret_cast<const bf16x8*>(buf + idx);
}
__device__ __forceinline__ bf16x8 gw_frag(const unsigned short* __restrict__ W, int wrow, int kof) {
  return *reinterpret_cast<const bf16x8*>(W + (size_t)wrow * HID + kof);
}
__device__ __forceinline__ uint4 gw_fragu(const unsigned short* __restrict__ W, int wrow, int kof) {
  return *reinterpret_cast<const uint4*>(W + (size_t)wrow * HID + kof);
}
__device__ __forceinline__ bf16x8 as_bf(uint4 u) { return __builtin_bit_cast(bf16x8, u); }
__device__ __forceinline__ uint2 pack4(f32x4 v) {
  uint2 r;
  r.x = (unsigned int)f2bf(v[0]) | ((unsigned int)f2bf(v[1]) << 16);
  r.y = (unsigned int)f2bf(v[2]) | ((unsigned int)f2bf(v[3]) << 16);
  return r;
}

// xpT layout: [T][NBLK][G3][8 rows]  -> per-(t,block8) slice is 12 KB contiguous,
//   fully dense in cache lines (the R10 concurrency fix).
// h0 slab  : [T][64][16 rows x 256 swizzled] (unchanged from R9; two 8-row
//   blocks fill the halves) so xp_gemm<0>'s fill needs no change.

// ================= phase 1 & 3: xp = A @ W^T ==========
template<int GATHER>
__global__ __launch_bounds__(NTHREADS)
void xp_gemm(const int* __restrict__ ids, const float* __restrict__ emb,
             const unsigned short* __restrict__ hsrc,
             const unsigned short* __restrict__ W,
             unsigned short* __restrict__ xpT)
{
  __shared__ __align__(16) unsigned short As[128 * HID];   // 64 KB
  const int tid = threadIdx.x;
  const int w = tid >> 6, lane = tid & 63, lr = lane & 15, lq = lane >> 4;
  const int bt = blockIdx.x & 63;          // batch tile (16 rows)
  const int tt = blockIdx.x >> 6;          // time tile 0..24
  const int r0 = bt * 16, t0 = tt * 8;

  for (int idx = tid; idx < 128 * 32; idx += NTHREADS) {
    int row = idx >> 5, cc = idx & 31;
    int bloc = row & 15, tloc = row >> 4;
    int sidx = row * HID + ((cc ^ (row & 7)) << 3);
    if (GATHER) {
      int rid = ids[(r0 + bloc) * T_LEN + t0 + tloc];
      const f32x4* src = reinterpret_cast<const f32x4*>(emb + (size_t)rid * HID + cc * 8);
      f32x4 v0 = src[0], v1 = src[1];
      uint4 pk;
      pk.x = (unsigned int)f2bf(v0[0]) | ((unsigned int)f2bf(v0[1]) << 16);
      pk.y = (unsigned int)f2bf(v0[2]) | ((unsigned int)f2bf(v0[3]) << 16);
      pk.z = (unsigned int)f2bf(v1[0]) | ((unsigned int)f2bf(v1[1]) << 16);
      pk.w = (unsigned int)f2bf(v1[2]) | ((unsigned int)f2bf(v1[3]) << 16);
      *reinterpret_cast<uint4*>(&As[sidx]) = pk;
    } else {
      const unsigned short* hs = hsrc + ((size_t)(t0 + tloc) * 64 + bt) * (ROWS * HID);
      uint4 v = *reinterpret_cast<const uint4*>(hs + bloc * HID + ((cc ^ (bloc & 7)) << 3));
      *reinterpret_cast<uint4*>(&As[sidx]) = v;
    }
  }
  __syncthreads();

  const int colbase = w * 96;              // wave owns 96 cols (3 pairs of 16)
  #pragma unroll 1
  for (int mt = 0; mt < 8; ++mt) {
    bf16x8 a[8];
    #pragma unroll
    for (int k = 0; k < 8; ++k) a[k] = lds_frag(As, mt * 16 + lr, k, lq);
    const int t = t0 + mt;
    // rows r0+lq*4..+3 -> block8 = r0/8 + (lq>>1), inner row offset (lq&1)*4
    unsigned short* xprow = xpT + ((size_t)t * NBLK + (r0 >> 3) + (lq >> 1)) * (G3 * RROWS)
                                + (lq & 1) * 4;
    #pragma unroll
    for (int np = 0; np < 3; ++np) {
      const int c0 = colbase + np * 32;
      f32x4 acc0 = {0,0,0,0}, acc1 = {0,0,0,0};
      #pragma unroll
      for (int k = 0; k < 8; ++k) {
        const int kof = k * 32 + lq * 8;
        bf16x8 b0 = gw_frag(W, c0 + lr,      kof);
        bf16x8 b1 = gw_frag(W, c0 + 16 + lr, kof);
        acc0 = __builtin_amdgcn_mfma_f32_16x16x32_bf16(a[k], b0, acc0, 0, 0, 0);
        acc1 = __builtin_amdgcn_mfma_f32_16x16x32_bf16(a[k], b1, acc1, 0, 0, 0);
      }
      *reinterpret_cast<uint2*>(xprow + (c0 + lr)      * RROWS) = pack4(acc0);
      *reinterpret_cast<uint2*>(xprow + (c0 + 16 + lr) * RROWS) = pack4(acc1);
    }
  }
}

// ================= phase 2: layer-0 recurrence, 128 blocks x 8 rows ==========
__global__ __launch_bounds__(NTHREADS, 2)
void gru_rec0(const unsigned short* __restrict__ xpT,
              const unsigned short* __restrict__ Whh,
              unsigned short* __restrict__ hout)
{
  __shared__ __align__(16) unsigned short hb[2][ROWS * HID];   // rows 8-15 stay zero
  const int tid = threadIdx.x;
  const int w = tid >> 6, lane = tid & 63, lr = lane & 15, lq = lane >> 4;
  const int b = blockIdx.x;
  const int c0 = w * 32;

  uint4 wf[2][3][8];
  #pragma unroll
  for (int j = 0; j < 2; ++j)
    #pragma unroll
    for (int g = 0; g < 3; ++g)
      #pragma unroll
      for (int k = 0; k < 8; ++k)
        wf[j][g][k] = gw_fragu(Whh, g * 256 + c0 + j * 16 + lr, k * 32 + lq * 8);
  #pragma unroll
  for (int j = 0; j < 2; ++j)
    #pragma unroll
    for (int g = 0; g < 3; ++g)
      #pragma unroll
      for (int k = 0; k < 8; ++k)
        asm volatile("" : "+a"(wf[j][g][k].x), "+a"(wf[j][g][k].y),
                          "+a"(wf[j][g][k].z), "+a"(wf[j][g][k].w));

  for (int i = tid; i < ROWS * HID; i += NTHREADS) { hb[0][i] = 0; hb[1][i] = 0; }

  f32x4 hreg[2] = {{0,0,0,0},{0,0,0,0}};

  const int rowoff = (lq & 1) * 4;                   // lq>=2 lanes alias (junk, masked)
  const int bj0 = (c0 + lr) * RROWS + rowoff;

  const size_t slabstep = (size_t)NBLK * G3 * RROWS;
  const unsigned short* slab = xpT + (size_t)b * (G3 * RROWS);
  unsigned short* hslab = hout + (size_t)(b >> 1) * (ROWS * HID) + (size_t)(b & 1) * (RROWS * HID);
  const size_t hstep = (size_t)64 * (ROWS * HID);

  __syncthreads();

  uint2 pz[2][3];
  #pragma unroll
  for (int g = 0; g < 3; ++g) {
    pz[0][g] = *reinterpret_cast<const uint2*>(slab + g * 2048 + bj0);
    pz[1][g] = *reinterpret_cast<const uint2*>(slab + g * 2048 + bj0 + 128);
  }

  int cur = 0;
  #pragma unroll 1
  for (int t = 0; t < T_LEN; ++t) {
    f32x4 acc[2][3];
    uint2 xn0 = pz[0][2], xn1 = pz[1][2];
    #pragma unroll
    for (int j = 0; j < 2; ++j) {
      #pragma unroll
      for (int g = 0; g < 2; ++g) {
        uint2 p = pz[j][g];
        f32x4 v;
        v[0] = bf2f(p.x & 0xffffu); v[1] = bf2f(p.x >> 16);
        v[2] = bf2f(p.y & 0xffffu); v[3] = bf2f(p.y >> 16);
        acc[j][g] = v;
      }
      f32x4 z4 = {0,0,0,0};
      acc[j][2] = z4;
    }

    {
      const unsigned short* slab2 = (t + 1 < T_LEN) ? slab + slabstep : slab;
      #pragma unroll
      for (int g = 0; g < 3; ++g) {
        pz[0][g] = *reinterpret_cast<const uint2*>(slab2 + g * 2048 + bj0);
        pz[1][g] = *reinterpret_cast<const uint2*>(slab2 + g * 2048 + bj0 + 128);
      }
    }

    asm volatile("s_waitcnt lgkmcnt(0)\n\ts_barrier" ::: "memory");

    // coalesced export of h(t-1): rows 0-7 = first 4 KB of the LDS tile
    if (t > 0 && tid < 256) {
      uint4 hv = *reinterpret_cast<const uint4*>(&hb[cur][tid * 8]);
      *reinterpret_cast<uint4*>(hslab + (size_t)(t - 1) * hstep + tid * 8) = hv;
    }

    #pragma unroll
    for (int k = 0; k < 8; ++k) {
      bf16x8 a = lds_frag(hb[cur], lr, k, lq);
      #pragma unroll
      for (int j = 0; j < 2; ++j) {
        acc[j][0] = __builtin_amdgcn_mfma_f32_16x16x32_bf16(a, as_bf(wf[j][0][k]), acc[j][0], 0, 0, 0);
        acc[j][1] = __builtin_amdgcn_mfma_f32_16x16x32_bf16(a, as_bf(wf[j][1][k]), acc[j][1], 0, 0, 0);
        acc[j][2] = __builtin_amdgcn_mfma_f32_16x16x32_bf16(a, as_bf(wf[j][2][k]), acc[j][2], 0, 0, 0);
      }
    }

    #pragma unroll
    for (int j = 0; j < 2; ++j) {
      uint2 xn = j ? xn1 : xn0;
      float xnv[4];
      xnv[0] = bf2f(xn.x & 0xffffu); xnv[1] = bf2f(xn.x >> 16);
      xnv[2] = bf2f(xn.y & 0xffffu); xnv[3] = bf2f(xn.y >> 16);
      #pragma unroll
      for (int q = 0; q < 4; ++q) {
        float r = sigm(acc[j][0][q]);
        float z = sigm(acc[j][1][q]);
        float n = tanh_f(xnv[q] + r * acc[j][2][q]);
        float hnew = fmaf(z, hreg[j][q] - n, n);   // n + z*(h-n)
        hreg[j][q] = hnew;
        if (lq < 2) {
          int m = lq * 4 + q;
          int c = c0 + j * 16 + lr;
          hb[cur ^ 1][m * HID + (((c >> 3) ^ (m & 7)) << 3) + (c & 7)] = f2bf(hnew);
        }
      }
    }
    slab += slabstep;
    cur ^= 1;
  }

  asm volatile("s_waitcnt lgkmcnt(0)\n\ts_barrier" ::: "memory");
  if (tid < 256) {
    uint4 hv = *reinterpret_cast<const uint4*>(&hb[cur][tid * 8]);
    *reinterpret_cast<uint4*>(hslab + (size_t)(T_LEN - 1) * hstep + tid * 8) = hv;
  }
}

// ================= phase 4: layer-1 recurrence + fused dense epilogue ==========
// Wd (64 dwords/wave) joins Whh1 (192) in AGPRs: 256 exact. Dense for step t-1
// runs at iteration-top t, sharing the LDS A-fragment reads with the hh-MFMA.
__global__ __launch_bounds__(NTHREADS, 2)
void gru_rec1(const unsigned short* __restrict__ xpT,
              const unsigned short* __restrict__ Whh,
              const unsigned short* __restrict__ Wd,
              const float* __restrict__ db,
              float* __restrict__ out)
{
  __shared__ __align__(16) unsigned short hb[2][ROWS * HID];
  const int tid = threadIdx.x;
  const int w = tid >> 6, lane = tid & 63, lr = lane & 15, lq = lane >> 4;
  const int b = blockIdx.x;
  const int r0 = b * RROWS;
  const int c0 = w * 32;

  uint4 wf[2][3][8];
  #pragma unroll
  for (int j = 0; j < 2; ++j)
    #pragma unroll
    for (int g = 0; g < 3; ++g)
      #pragma unroll
      for (int k = 0; k < 8; ++k)
        wf[j][g][k] = gw_fragu(Whh, g * 256 + c0 + j * 16 + lr, k * 32 + lq * 8);
  uint4 wfd[2][8];
  #pragma unroll
  for (int j = 0; j < 2; ++j)
    #pragma unroll
    for (int k = 0; k < 8; ++k)
      wfd[j][k] = gw_fragu(Wd, c0 + j * 16 + lr, k * 32 + lq * 8);
  #pragma unroll
  for (int j = 0; j < 2; ++j)
    #pragma unroll
    for (int g = 0; g < 3; ++g)
      #pragma unroll
      for (int k = 0; k < 8; ++k)
        asm volatile("" : "+a"(wf[j][g][k].x), "+a"(wf[j][g][k].y),
                          "+a"(wf[j][g][k].z), "+a"(wf[j][g][k].w));
  #pragma unroll
  for (int j = 0; j < 2; ++j)
    #pragma unroll
    for (int k = 0; k < 8; ++k)
      asm volatile("" : "+a"(wfd[j][k].x), "+a"(wfd[j][k].y),
                        "+a"(wfd[j][k].z), "+a"(wfd[j][k].w));

  for (int i = tid; i < ROWS * HID; i += NTHREADS) { hb[0][i] = 0; hb[1][i] = 0; }

  f32x4 hreg[2] = {{0,0,0,0},{0,0,0,0}};
  const float b0v = db[c0 + lr];
  const float b1v = db[c0 + 16 + lr];

  const int rowoff = (lq & 1) * 4;
  const int bj0 = (c0 + lr) * RROWS + rowoff;

  const size_t slabstep = (size_t)NBLK * G3 * RROWS;
  const unsigned short* slab = xpT + (size_t)b * (G3 * RROWS);

  __syncthreads();

  uint2 pz[2][3];
  #pragma unroll
  for (int g = 0; g < 3; ++g) {
    pz[0][g] = *reinterpret_cast<const uint2*>(slab + g * 2048 + bj0);
    pz[1][g] = *reinterpret_cast<const uint2*>(slab + g * 2048 + bj0 + 128);
  }

  int cur = 0;
  #pragma unroll 1
  for (int t = 0; t < T_LEN; ++t) {
    f32x4 acc[2][3];
    uint2 xn0 = pz[0][2], xn1 = pz[1][2];
    #pragma unroll
    for (int j = 0; j < 2; ++j) {
      #pragma unroll
      for (int g = 0; g < 2; ++g) {
        uint2 p = pz[j][g];
        f32x4 v;
        v[0] = bf2f(p.x & 0xffffu); v[1] = bf2f(p.x >> 16);
        v[2] = bf2f(p.y & 0xffffu); v[3] = bf2f(p.y >> 16);
        acc[j][g] = v;
      }
      f32x4 z4 = {0,0,0,0};
      acc[j][2] = z4;
    }

    {
      const unsigned short* slab2 = (t + 1 < T_LEN) ? slab + slabstep : slab;
      #pragma unroll
      for (int g = 0; g < 3; ++g) {
        pz[0][g] = *reinterpret_cast<const uint2*>(slab2 + g * 2048 + bj0);
        pz[1][g] = *reinterpret_cast<const uint2*>(slab2 + g * 2048 + bj0 + 128);
      }
    }

    asm volatile("s_waitcnt lgkmcnt(0)\n\ts_barrier" ::: "memory");

    // shared A-fragments: h1(t-1) from LDS, used by dense(t-1) AND hh(t)
    bf16x8 a[8];
    #pragma unroll
    for (int k = 0; k < 8; ++k) a[k] = lds_frag(hb[cur], lr, k, lq);

    // dense epilogue for step t-1
    if (t > 0) {
      f32x4 d0 = {0,0,0,0}, d1 = {0,0,0,0};
      #pragma unroll
      for (int k = 0; k < 8; ++k) {
        d0 = __builtin_amdgcn_mfma_f32_16x16x32_bf16(a[k], as_bf(wfd[0][k]), d0, 0, 0, 0);
        d1 = __builtin_amdgcn_mfma_f32_16x16x32_bf16(a[k], as_bf(wfd[1][k]), d1, 0, 0, 0);
      }
      if (lq < 2) {
        #pragma unroll
        for (int q = 0; q < 4; ++q) {
          size_t base = ((size_t)(r0 + lq * 4 + q) * T_LEN + (t - 1)) * HID;
          out[base + c0 + lr]      = d0[q] + b0v;
          out[base + c0 + 16 + lr] = d1[q] + b1v;
        }
      }
    }

    #pragma unroll
    for (int k = 0; k < 8; ++k) {
      #pragma unroll
      for (int j = 0; j < 2; ++j) {
        acc[j][0] = __builtin_amdgcn_mfma_f32_16x16x32_bf16(a[k], as_bf(wf[j][0][k]), acc[j][0], 0, 0, 0);
        acc[j][1] = __builtin_amdgcn_mfma_f32_16x16x32_bf16(a[k], as_bf(wf[j][1][k]), acc[j][1], 0, 0, 0);
        acc[j][2] = __builtin_amdgcn_mfma_f32_16x16x32_bf16(a[k], as_bf(wf[j][2][k]), acc[j][2], 0, 0, 0);
      }
    }

    #pragma unroll
    for (int j = 0; j < 2; ++j) {
      uint2 xn = j ? xn1 : xn0;
      float xnv[4];
      xnv[0] = bf2f(xn.x & 0xffffu); xnv[1] = bf2f(xn.x >> 16);
      xnv[2] = bf2f(xn.y & 0xffffu); xnv[3] = bf2f(xn.y >> 16);
      #pragma unroll
      for (int q = 0; q < 4; ++q) {
        float r = sigm(acc[j][0][q]);
        float z = sigm(acc[j][1][q]);
        float n = tanh_f(xnv[q] + r * acc[j][2][q]);
        float hnew = fmaf(z, hreg[j][q] - n, n);
        hreg[j][q] = hnew;
        if (lq < 2) {
          int m = lq * 4 + q;
          int c = c0 + j * 16 + lr;
          hb[cur ^ 1][m * HID + (((c >> 3) ^ (m & 7)) << 3) + (c & 7)] = f2bf(hnew);
        }
      }
    }
    slab += slabstep;
    cur ^= 1;
  }

  // epilogue: dense for t = T-1
  asm volatile("s_waitcnt lgkmcnt(0)\n\ts_barrier" ::: "memory");
  {
    bf16x8 a[8];
    #pragma unroll
    for (int k = 0; k < 8; ++k) a[k] = lds_frag(hb[cur], lr, k, lq);
    f32x4 d0 = {0,0,0,0}, d1 = {0,0,0,0};
    #pragma unroll
    for (int k = 0; k < 8; ++k) {
      d0 = __builtin_amdgcn_mfma_f32_16x16x32_bf16(a[k], as_bf(wfd[0][k]), d0, 0, 0, 0);
      d1 = __builtin_amdgcn_mfma_f32_16x16x32_bf16(a[k], as_bf(wfd[1][k]), d1, 0, 0, 0);
    }
    if (lq < 2) {
      #pragma unroll
      for (int q = 0; q < 4; ++q) {
        size_t base = ((size_t)(r0 + lq * 4 + q) * T_LEN + (T_LEN - 1)) * HID;
        out[base + c0 + lr]      = d0[q] + b0v;
        out[base + c0 + 16 + lr] = d1[q] + b1v;
      }
    }
  }
}

// ================= fallback (small ws): round-1 fused kernel ==========
__device__ __forceinline__ void layer_step(
    const bf16x8* ax, const bf16x8* ah,
    const unsigned short* __restrict__ Wih,
    const unsigned short* __restrict__ Whh,
    float (&hreg)[2][4],
    unsigned short* __restrict__ outb,
    int c0base, int lr, int lq)
{
  #pragma unroll
  for (int j = 0; j < 2; ++j) {
    const int c0 = c0base + j * 16;
    f32x4 xr = {0,0,0,0}, xz = {0,0,0,0}, xn = {0,0,0,0};
    f32x4 hr = {0,0,0,0}, hz = {0,0,0,0}, hn = {0,0,0,0};
    #pragma unroll
    for (int k = 0; k < 8; ++k) {
      const int kof = k * 32 + lq * 8;
      bf16x8 b0 = gw_frag(Wih,       c0 + lr, kof);
      bf16x8 b1 = gw_frag(Wih, 256 + c0 + lr, kof);
      bf16x8 b2 = gw_frag(Wih, 512 + c0 + lr, kof);
      bf16x8 w0 = gw_frag(Whh,       c0 + lr, kof);
      bf16x8 w1 = gw_frag(Whh, 256 + c0 + lr, kof);
      bf16x8 w2 = gw_frag(Whh, 512 + c0 + lr, kof);
      xr = __builtin_amdgcn_mfma_f32_16x16x32_bf16(ax[k], b0, xr, 0, 0, 0);
      xz = __builtin_amdgcn_mfma_f32_16x16x32_bf16(ax[k], b1, xz, 0, 0, 0);
      xn = __builtin_amdgcn_mfma_f32_16x16x32_bf16(ax[k], b2, xn, 0, 0, 0);
      hr = __builtin_amdgcn_mfma_f32_16x16x32_bf16(ah[k], w0, hr, 0, 0, 0);
      hz = __builtin_amdgcn_mfma_f32_16x16x32_bf16(ah[k], w1, hz, 0, 0, 0);
      hn = __builtin_amdgcn_mfma_f32_16x16x32_bf16(ah[k], w2, hn, 0, 0, 0);
    }
    #pragma unroll
    for (int q = 0; q < 4; ++q) {
      float r = sigm(xr[q] + hr[q]);
      float z = sigm(xz[q] + hz[q]);
      float n = tanh_f(xn[q] + r * hn[q]);
      float h = (1.0f - z) * n + z * hreg[j][q];
      hreg[j][q] = h;
      int m = lq * 4 + q;
      int c = c0 + lr;
      int idx = m * HID + (((c >> 3) ^ (m & 7)) << 3) + (c & 7);
      outb[idx] = f2bf(h);
    }
  }
}

__global__ __launch_bounds__(NTHREADS)
void gru_fused(const int* __restrict__ ids,
               const float* __restrict__ emb,
               const unsigned short* __restrict__ wbf,
               const float* __restrict__ dense_b,
               float* __restrict__ out)
{
  __shared__ __align__(16) unsigned short x_bf[ROWS * HID];
  __shared__ __align__(16) unsigned short h0b[2][ROWS * HID];
  __shared__ __align__(16) unsigned short h1b[2][ROWS * HID];

  const int tid  = threadIdx.x;
  const int w    = tid >> 6;
  const int lane = tid & 63;
  const int lr   = lane & 15;
  const int lq   = lane >> 4;
  const int r0   = blockIdx.x * ROWS;
  const int c0base = w * 32;

  const unsigned short* Wih0 = wbf;
  const unsigned short* Whh0 = wbf + 1 * WSZ;
  const unsigned short* Wih1 = wbf + 2 * WSZ;
  const unsigned short* Whh1 = wbf + 3 * WSZ;
  const unsigned short* Wd   = wbf + 4 * WSZ;

  for (int i = tid; i < ROWS * HID; i += NTHREADS) {
    h0b[0][i] = 0; h0b[1][i] = 0; h1b[0][i] = 0; h1b[1][i] = 0;
  }
  float hreg0[2][4] = {}; float hreg1[2][4] = {};
  const float bias0 = dense_b[c0base + lr];
  const float bias1 = dense_b[c0base + 16 + lr];

  const int grow   = tid >> 5;
  const int gchunk = tid & 31;
  const int gswz   = grow * HID + ((gchunk ^ (grow & 7)) << 3);
  const int gid_base = (r0 + grow) * T_LEN;

  __syncthreads();

  int cur = 0;
  for (int t = 0; t < T_LEN; ++t) {
    {
      int rid = ids[gid_base + t];
      const f32x4* src = reinterpret_cast<const f32x4*>(emb + (size_t)rid * HID + gchunk * 8);
      f32x4 v0 = src[0];
      f32x4 v1 = src[1];
      uint4 pk;
      pk.x = (unsigned int)f2bf(v0[0]) | ((unsigned int)f2bf(v0[1]) << 16);
      pk.y = (unsigned int)f2bf(v0[2]) | ((unsigned int)f2bf(v0[3]) << 16);
      pk.z = (unsigned int)f2bf(v1[0]) | ((unsigned int)f2bf(v1[1]) << 16);
      pk.w = (unsigned int)f2bf(v1[2]) | ((unsigned int)f2bf(v1[3]) << 16);
      *reinterpret_cast<uint4*>(&x_bf[gswz]) = pk;
    }
    __syncthreads();

    bf16x8 ax[8], ah[8];
    #pragma unroll
    for (int k = 0; k < 8; ++k) {
      ax[k] = lds_frag(x_bf,     lr, k, lq);
      ah[k] = lds_frag(h0b[cur], lr, k, lq);
    }
    layer_step(ax, ah, Wih0, Whh0, hreg0, h0b[cur ^ 1], c0base, lr, lq);
    __syncthreads();

    #pragma unroll
    for (int k = 0; k < 8; ++k) {
      ax[k] = lds_frag(h0b[cur ^ 1], lr, k, lq);
      ah[k] = lds_frag(h1b[cur],     lr, k, lq);
    }
    layer_step(ax, ah, Wih1, Whh1, hreg1, h1b[cur ^ 1], c0base, lr, lq);
    __syncthreads();

    #pragma unroll
    for (int k = 0; k < 8; ++k) ax[k] = lds_frag(h1b[cur ^ 1], lr, k, lq);
    #pragma unroll
    for (int j = 0; j < 2; ++j) {
      const int c0 = c0base + j * 16;
      f32x4 acc = {0,0,0,0};
      #pragma unroll
      for (int k = 0; k < 8; ++k) {
        bf16x8 bw = gw_frag(Wd, c0 + lr, k * 32 + lq * 8);
        acc = __builtin_amdgcn_mfma_f32_16x16x32_bf16(ax[k], bw, acc, 0, 0, 0);
      }
      const float bias = j ? bias1 : bias0;
      size_t base = ((size_t)(r0 + lq * 4) * T_LEN + t) * HID + c0 + lr;
      #pragma unroll
      for (int q = 0; q < 4; ++q) {
        out[base + (size_t)q * T_LEN * HID] = acc[q] + bias;
      }
    }
    cur ^= 1;
  }
}

extern "C" void kernel_launch(void* const* d_in, const int* in_sizes, int n_in,
                              void* d_out, int out_size, void* d_ws, size_t ws_size,
                              hipStream_t stream) {
  const int*   ids  = (const int*)d_in[0];
  const float* emb  = (const float*)d_in[1];
  const float* wih0 = (const float*)d_in[2];
  const float* whh0 = (const float*)d_in[3];
  const float* wih1 = (const float*)d_in[4];
  const float* whh1 = (const float*)d_in[5];
  const float* dw   = (const float*)d_in[6];
  const float* db   = (const float*)d_in[7];

  unsigned short* wbf = (unsigned short*)d_ws;   // 851968 bf16 = 1.7 MB

  const int total = 4 * WSZ + HID * HID;
  convert_weights<<<(total + 255) / 256, 256, 0, stream>>>(wih0, whh0, wih1, whh1, dw, wbf);

  const size_t XP_OFF = 2u * 1024u * 1024u;
  const size_t XP_BYTES = (size_t)T_LEN * G3 * BATCH * 2;        // 314,572,800
  const size_t H_OFF  = XP_OFF + XP_BYTES;
  const size_t H_BYTES = (size_t)BATCH * T_LEN * HID * 2;        // 104,857,600
  const size_t NEED = H_OFF + H_BYTES;                           // ~421.5 MB

  if (ws_size >= NEED) {
    unsigned short* xpT  = (unsigned short*)((char*)d_ws + XP_OFF);
    unsigned short* hbuf = (unsigned short*)((char*)d_ws + H_OFF);
    const unsigned short* Wih0 = wbf;
    const unsigned short* Whh0 = wbf + 1 * WSZ;
    const unsigned short* Wih1 = wbf + 2 * WSZ;
    const unsigned short* Whh1 = wbf + 3 * WSZ;
    const unsigned short* Wd   = wbf + 4 * WSZ;

    xp_gemm<1><<<1600, NTHREADS, 0, stream>>>(ids, emb, nullptr, Wih0, xpT);
    gru_rec0<<<NBLK, NTHREADS, 0, stream>>>(xpT, Whh0, hbuf);
    xp_gemm<0><<<1600, NTHREADS, 0, stream>>>(nullptr, nullptr, hbuf, Wih1, xpT);
    gru_rec1<<<NBLK, NTHREADS, 0, stream>>>(xpT, Whh1, Wd, db, (float*)d_out);
  } else {
    gru_fused<<<64, NTHREADS, 0, stream>>>(ids, emb, wbf, db, (float*)d_out);
  }
}

// Round 11
// 2151.398 us; speedup vs baseline: 1.9501x; 1.9501x over previous
//
#include <hip/hip_runtime.h>

#define T_LEN 200
#define HID   256
#define BATCH 1024
#define G3    768
#define ROWS  16
#define NTHREADS 512
#define WSZ   196608   // 768*256 elements per GRU weight matrix

typedef __bf16  bf16x8 __attribute__((ext_vector_type(8)));
typedef float   f32x4  __attribute__((ext_vector_type(4)));

__device__ __forceinline__ unsigned short f2bf(float f) {
  union { float f; unsigned int u; } c; c.f = f;
  unsigned int u = c.u;
  u += 0x7FFFu + ((u >> 16) & 1u);     // round-to-nearest-even
  return (unsigned short)(u >> 16);
}
__device__ __forceinline__ float bf2f(unsigned int u16v) {
  union { unsigned int u; float f; } c; c.u = u16v << 16; return c.f;
}
__device__ __forceinline__ float sigm(float x) { return 1.0f / (1.0f + __expf(-x)); }
__device__ __forceinline__ float tanh_f(float x) { return 1.0f - 2.0f / (__expf(2.0f * x) + 1.0f); }

__global__ void convert_weights(const float* __restrict__ a,
                                const float* __restrict__ b,
                                const float* __restrict__ c,
                                const float* __restrict__ d,
                                const float* __restrict__ e,
                                unsigned short* __restrict__ out) {
  int i = blockIdx.x * blockDim.x + threadIdx.x;
  const int total = 4 * WSZ + HID * HID;
  if (i >= total) return;
  float v;
  if      (i < 1 * WSZ) v = a[i];
  else if (i < 2 * WSZ) v = b[i - 1 * WSZ];
  else if (i < 3 * WSZ) v = c[i - 2 * WSZ];
  else if (i < 4 * WSZ) v = d[i - 3 * WSZ];
  else                  v = e[i - 4 * WSZ];
  out[i] = f2bf(v);
}

__device__ __forceinline__ bf16x8 lds_frag(const unsigned short* buf, int row, int k, int lq) {
  int chunk = (k << 2) + lq;
  int idx = row * HID + ((chunk ^ (row & 7)) << 3);
  return *reinterpret_cast<const bf16x8*>(buf + idx);
}
__device__ __forceinline__ bf16x8 gw_frag(const unsigned short* __restrict__ W, int wrow, int kof) {
  return *reinterpret_cast<const bf16x8*>(W + (size_t)wrow * HID + kof);
}
__device__ __forceinline__ uint4 gw_fragu(const unsigned short* __restrict__ W, int wrow, int kof) {
  return *reinterpret_cast<const uint4*>(W + (size_t)wrow * HID + kof);
}
__device__ __forceinline__ bf16x8 as_bf(uint4 u) { return __builtin_bit_cast(bf16x8, u); }
__device__ __forceinline__ uint2 pack4(f32x4 v) {
  uint2 r;
  r.x = (unsigned int)f2bf(v[0]) | ((unsigned int)f2bf(v[1]) << 16);
  r.y = (unsigned int)f2bf(v[2]) | ((unsigned int)f2bf(v[3]) << 16);
  return r;
}

// xpT layout: [T][batch_tile(64)][G3][16 batch]  (24 KB contiguous per (t,bt))
// ================= phase 1 & 3: xp = A @ W^T ==========
template<int GATHER>
__global__ __launch_bounds__(NTHREADS)
void xp_gemm(const int* __restrict__ ids, const float* __restrict__ emb,
             const unsigned short* __restrict__ hsrc,
             const unsigned short* __restrict__ W,
             unsigned short* __restrict__ xpT)
{
  __shared__ __align__(16) unsigned short As[128 * HID];   // 64 KB
  const int tid = threadIdx.x;
  const int w = tid >> 6, lane = tid & 63, lr = lane & 15, lq = lane >> 4;
  const int bt = blockIdx.x & 63;          // batch tile
  const int tt = blockIdx.x >> 6;          // time tile 0..24
  const int r0 = bt * 16, t0 = tt * 8;

  for (int idx = tid; idx < 128 * 32; idx += NTHREADS) {
    int row = idx >> 5, cc = idx & 31;
    int bloc = row & 15, tloc = row >> 4;
    int sidx = row * HID + ((cc ^ (row & 7)) << 3);
    if (GATHER) {
      int rid = ids[(r0 + bloc) * T_LEN + t0 + tloc];
      const f32x4* src = reinterpret_cast<const f32x4*>(emb + (size_t)rid * HID + cc * 8);
      f32x4 v0 = src[0], v1 = src[1];
      uint4 pk;
      pk.x = (unsigned int)f2bf(v0[0]) | ((unsigned int)f2bf(v0[1]) << 16);
      pk.y = (unsigned int)f2bf(v0[2]) | ((unsigned int)f2bf(v0[3]) << 16);
      pk.z = (unsigned int)f2bf(v1[0]) | ((unsigned int)f2bf(v1[1]) << 16);
      pk.w = (unsigned int)f2bf(v1[2]) | ((unsigned int)f2bf(v1[3]) << 16);
      *reinterpret_cast<uint4*>(&As[sidx]) = pk;
    } else {
      uint4 v = *reinterpret_cast<const uint4*>(hsrc + ((size_t)(r0 + bloc) * T_LEN + t0 + tloc) * HID + cc * 8);
      *reinterpret_cast<uint4*>(&As[sidx]) = v;
    }
  }
  __syncthreads();

  const int colbase = w * 96;              // wave owns 96 cols (3 pairs of 16)
  #pragma unroll 1
  for (int mt = 0; mt < 8; ++mt) {
    bf16x8 a[8];
    #pragma unroll
    for (int k = 0; k < 8; ++k) a[k] = lds_frag(As, mt * 16 + lr, k, lq);
    const int t = t0 + mt;
    unsigned short* xprow = xpT + ((size_t)t * 64 + bt) * (G3 * 16);
    #pragma unroll
    for (int np = 0; np < 3; ++np) {
      const int c0 = colbase + np * 32;
      f32x4 acc0 = {0,0,0,0}, acc1 = {0,0,0,0};
      #pragma unroll
      for (int k = 0; k < 8; ++k) {
        const int kof = k * 32 + lq * 8;
        bf16x8 b0 = gw_frag(W, c0 + lr,      kof);
        bf16x8 b1 = gw_frag(W, c0 + 16 + lr, kof);
        acc0 = __builtin_amdgcn_mfma_f32_16x16x32_bf16(a[k], b0, acc0, 0, 0, 0);
        acc1 = __builtin_amdgcn_mfma_f32_16x16x32_bf16(a[k], b1, acc1, 0, 0, 0);
      }
      *reinterpret_cast<uint2*>(xprow + (c0 + lr)      * 16 + lq * 4) = pack4(acc0);
      *reinterpret_cast<uint2*>(xprow + (c0 + 16 + lr) * 16 + lq * 4) = pack4(acc1);
    }
  }
}

// ================= phase 2 & 4: recurrent GRU layer ==========
// R10 post-mortem resolved the 5-round mystery: at 2 waves/SIMD the per-wave
// UNIFIED budget is 256 regs (VGPR+AGPR share the file, m69/m08). Demand was
// 192 weights + ~120 arch ~= 312 -> the allocator ALWAYS spilled ~weights to
// L2-resident scratch (invisible in FETCH), giving the invariant ~4.4us/step
// L2-reload floor in R5-R9. Fix (single delta vs the proven R8 kernel):
// "+a" pins the 192 weight dwords to AGPR (hard class constraint), and
// amdgpu_waves_per_eu(2,2) grants the 256-reg budget, forcing the arch
// working set into <=64 VGPRs -> true residency, zero per-step reload.
__global__ __launch_bounds__(NTHREADS)
__attribute__((amdgpu_waves_per_eu(2, 2)))
void gru_rec(const unsigned short* __restrict__ xpT,
             const unsigned short* __restrict__ Whh,
             unsigned short* __restrict__ hout)
{
  __shared__ __align__(16) unsigned short hb[2][ROWS * HID];   // 16 KB double buffer
  const int tid = threadIdx.x;
  const int w = tid >> 6, lane = tid & 63, lr = lane & 15, lq = lane >> 4;
  const int bt = blockIdx.x;
  const int r0 = bt * ROWS;
  const int c0 = w * 32;

  // Whh fragments for this wave's 32 cols x 3 gates: 192 dwords pinned to AGPR.
  uint4 wf[2][3][8];
  #pragma unroll
  for (int j = 0; j < 2; ++j)
    #pragma unroll
    for (int g = 0; g < 3; ++g)
      #pragma unroll
      for (int k = 0; k < 8; ++k)
        wf[j][g][k] = gw_fragu(Whh, g * 256 + c0 + j * 16 + lr, k * 32 + lq * 8);
  #pragma unroll
  for (int j = 0; j < 2; ++j)
    #pragma unroll
    for (int g = 0; g < 3; ++g)
      #pragma unroll
      for (int k = 0; k < 8; ++k)
        asm volatile("" : "+a"(wf[j][g][k].x), "+a"(wf[j][g][k].y),
                          "+a"(wf[j][g][k].z), "+a"(wf[j][g][k].w));

  for (int i = tid; i < ROWS * HID; i += NTHREADS) { hb[0][i] = 0; }

  f32x4 hreg[2] = {{0,0,0,0},{0,0,0,0}};

  const int bj0 = (c0 + lr) * 16 + lq * 4;

  const size_t slabstep = (size_t)64 * G3 * 16;
  const unsigned short* slab = xpT + (size_t)bt * (G3 * 16);

  __syncthreads();   // covers hb zero-init (one-time vmcnt drain is harmless)

  // prefetch all gates for t=0
  uint2 pz[2][3];
  #pragma unroll
  for (int g = 0; g < 3; ++g) {
    pz[0][g] = *reinterpret_cast<const uint2*>(slab + g * 4096 + bj0);
    pz[1][g] = *reinterpret_cast<const uint2*>(slab + g * 4096 + bj0 + 256);
  }

  int cur = 0;
  #pragma unroll 1
  for (int t = 0; t < T_LEN; ++t) {
    // consume prefetched xp: seed r,z accumulators; keep xn packed in regs
    f32x4 acc[2][3];
    uint2 xn0 = pz[0][2], xn1 = pz[1][2];
    #pragma unroll
    for (int j = 0; j < 2; ++j) {
      #pragma unroll
      for (int g = 0; g < 2; ++g) {
        uint2 p = pz[j][g];
        f32x4 v;
        v[0] = bf2f(p.x & 0xffffu); v[1] = bf2f(p.x >> 16);
        v[2] = bf2f(p.y & 0xffffu); v[3] = bf2f(p.y >> 16);
        acc[j][g] = v;
      }
      f32x4 z4 = {0,0,0,0};
      acc[j][2] = z4;
    }

    // prefetch next step (barrier below does NOT drain vmcnt)
    {
      const unsigned short* slab2 = (t + 1 < T_LEN) ? slab + slabstep : slab;
      #pragma unroll
      for (int g = 0; g < 3; ++g) {
        pz[0][g] = *reinterpret_cast<const uint2*>(slab2 + g * 4096 + bj0);
        pz[1][g] = *reinterpret_cast<const uint2*>(slab2 + g * 4096 + bj0 + 256);
      }
    }

    // LDS-only barrier: wait own ds ops, then s_barrier. No vmcnt(0) drain.
    asm volatile("s_waitcnt lgkmcnt(0)\n\ts_barrier" ::: "memory");

    #pragma unroll
    for (int k = 0; k < 8; ++k) {
      bf16x8 a = lds_frag(hb[cur], lr, k, lq);
      #pragma unroll
      for (int j = 0; j < 2; ++j) {
        acc[j][0] = __builtin_amdgcn_mfma_f32_16x16x32_bf16(a, as_bf(wf[j][0][k]), acc[j][0], 0, 0, 0);
        acc[j][1] = __builtin_amdgcn_mfma_f32_16x16x32_bf16(a, as_bf(wf[j][1][k]), acc[j][1], 0, 0, 0);
        acc[j][2] = __builtin_amdgcn_mfma_f32_16x16x32_bf16(a, as_bf(wf[j][2][k]), acc[j][2], 0, 0, 0);
      }
    }

    #pragma unroll
    for (int j = 0; j < 2; ++j) {
      uint2 xn = j ? xn1 : xn0;
      float xnv[4];
      xnv[0] = bf2f(xn.x & 0xffffu); xnv[1] = bf2f(xn.x >> 16);
      xnv[2] = bf2f(xn.y & 0xffffu); xnv[3] = bf2f(xn.y >> 16);
      #pragma unroll
      for (int q = 0; q < 4; ++q) {
        float r = sigm(acc[j][0][q]);
        float z = sigm(acc[j][1][q]);
        float n = tanh_f(xnv[q] + r * acc[j][2][q]);
        float hnew = fmaf(z, hreg[j][q] - n, n);   // (1-z)*n + z*h
        hreg[j][q] = hnew;
        unsigned short hb16 = f2bf(hnew);
        int m = lq * 4 + q;
        int c = c0 + j * 16 + lr;
        hb[cur ^ 1][m * HID + (((c >> 3) ^ (m & 7)) << 3) + (c & 7)] = hb16;
        hout[((size_t)(r0 + m) * T_LEN + t) * HID + c] = hb16;
      }
    }
    slab += slabstep;
    cur ^= 1;
  }
}

// ================= phase 5: out = h1 @ Wd^T + b (fp32 out) ==========
__global__ __launch_bounds__(NTHREADS)
void dense_gemm(const unsigned short* __restrict__ hsrc,
                const unsigned short* __restrict__ Wd,
                const float* __restrict__ db,
                float* __restrict__ out)
{
  __shared__ __align__(16) unsigned short As[128 * HID];
  const int tid = threadIdx.x;
  const int w = tid >> 6, lane = tid & 63, lr = lane & 15, lq = lane >> 4;
  const int bt = blockIdx.x & 63;
  const int tt = blockIdx.x >> 6;
  const int r0 = bt * 16, t0 = tt * 8;

  for (int idx = tid; idx < 128 * 32; idx += NTHREADS) {
    int row = idx >> 5, cc = idx & 31;
    int bloc = row & 15, tloc = row >> 4;
    int sidx = row * HID + ((cc ^ (row & 7)) << 3);
    uint4 v = *reinterpret_cast<const uint4*>(hsrc + ((size_t)(r0 + bloc) * T_LEN + t0 + tloc) * HID + cc * 8);
    *reinterpret_cast<uint4*>(&As[sidx]) = v;
  }
  __syncthreads();

  const int c0 = w * 32;
  const float b0v = db[c0 + lr];
  const float b1v = db[c0 + 16 + lr];

  #pragma unroll 1
  for (int mt = 0; mt < 8; ++mt) {
    bf16x8 a[8];
    #pragma unroll
    for (int k = 0; k < 8; ++k) a[k] = lds_frag(As, mt * 16 + lr, k, lq);
    f32x4 acc0 = {0,0,0,0}, acc1 = {0,0,0,0};
    #pragma unroll
    for (int k = 0; k < 8; ++k) {
      const int kof = k * 32 + lq * 8;
      bf16x8 b0 = gw_frag(Wd, c0 + lr,      kof);
      bf16x8 b1 = gw_frag(Wd, c0 + 16 + lr, kof);
      acc0 = __builtin_amdgcn_mfma_f32_16x16x32_bf16(a[k], b0, acc0, 0, 0, 0);
      acc1 = __builtin_amdgcn_mfma_f32_16x16x32_bf16(a[k], b1, acc1, 0, 0, 0);
    }
    const int t = t0 + mt;
    #pragma unroll
    for (int q = 0; q < 4; ++q) {
      size_t base = ((size_t)(r0 + lq * 4 + q) * T_LEN + t) * HID;
      out[base + c0 + lr]      = acc0[q] + b0v;
      out[base + c0 + 16 + lr] = acc1[q] + b1v;
    }
  }
}

// ================= fallback (small ws): round-1 fused kernel ==========
__device__ __forceinline__ void layer_step(
    const bf16x8* ax, const bf16x8* ah,
    const unsigned short* __restrict__ Wih,
    const unsigned short* __restrict__ Whh,
    float (&hreg)[2][4],
    unsigned short* __restrict__ outb,
    int c0base, int lr, int lq)
{
  #pragma unroll
  for (int j = 0; j < 2; ++j) {
    const int c0 = c0base + j * 16;
    f32x4 xr = {0,0,0,0}, xz = {0,0,0,0}, xn = {0,0,0,0};
    f32x4 hr = {0,0,0,0}, hz = {0,0,0,0}, hn = {0,0,0,0};
    #pragma unroll
    for (int k = 0; k < 8; ++k) {
      const int kof = k * 32 + lq * 8;
      bf16x8 b0 = gw_frag(Wih,       c0 + lr, kof);
      bf16x8 b1 = gw_frag(Wih, 256 + c0 + lr, kof);
      bf16x8 b2 = gw_frag(Wih, 512 + c0 + lr, kof);
      bf16x8 w0 = gw_frag(Whh,       c0 + lr, kof);
      bf16x8 w1 = gw_frag(Whh, 256 + c0 + lr, kof);
      bf16x8 w2 = gw_frag(Whh, 512 + c0 + lr, kof);
      xr = __builtin_amdgcn_mfma_f32_16x16x32_bf16(ax[k], b0, xr, 0, 0, 0);
      xz = __builtin_amdgcn_mfma_f32_16x16x32_bf16(ax[k], b1, xz, 0, 0, 0);
      xn = __builtin_amdgcn_mfma_f32_16x16x32_bf16(ax[k], b2, xn, 0, 0, 0);
      hr = __builtin_amdgcn_mfma_f32_16x16x32_bf16(ah[k], w0, hr, 0, 0, 0);
      hz = __builtin_amdgcn_mfma_f32_16x16x32_bf16(ah[k], w1, hz, 0, 0, 0);
      hn = __builtin_amdgcn_mfma_f32_16x16x32_bf16(ah[k], w2, hn, 0, 0, 0);
    }
    #pragma unroll
    for (int q = 0; q < 4; ++q) {
      float r = sigm(xr[q] + hr[q]);
      float z = sigm(xz[q] + hz[q]);
      float n = tanh_f(xn[q] + r * hn[q]);
      float h = (1.0f - z) * n + z * hreg[j][q];
      hreg[j][q] = h;
      int m = lq * 4 + q;
      int c = c0 + lr;
      int idx = m * HID + (((c >> 3) ^ (m & 7)) << 3) + (c & 7);
      outb[idx] = f2bf(h);
    }
  }
}

__global__ __launch_bounds__(NTHREADS)
void gru_fused(const int* __restrict__ ids,
               const float* __restrict__ emb,
               const unsigned short* __restrict__ wbf,
               const float* __restrict__ dense_b,
               float* __restrict__ out)
{
  __shared__ __align__(16) unsigned short x_bf[ROWS * HID];
  __shared__ __align__(16) unsigned short h0b[2][ROWS * HID];
  __shared__ __align__(16) unsigned short h1b[2][ROWS * HID];

  const int tid  = threadIdx.x;
  const int w    = tid >> 6;
  const int lane = tid & 63;
  const int lr   = lane & 15;
  const int lq   = lane >> 4;
  const int r0   = blockIdx.x * ROWS;
  const int c0base = w * 32;

  const unsigned short* Wih0 = wbf;
  const unsigned short* Whh0 = wbf + 1 * WSZ;
  const unsigned short* Wih1 = wbf + 2 * WSZ;
  const unsigned short* Whh1 = wbf + 3 * WSZ;
  const unsigned short* Wd   = wbf + 4 * WSZ;

  for (int i = tid; i < ROWS * HID; i += NTHREADS) {
    h0b[0][i] = 0; h0b[1][i] = 0; h1b[0][i] = 0; h1b[1][i] = 0;
  }
  float hreg0[2][4] = {}; float hreg1[2][4] = {};
  const float bias0 = dense_b[c0base + lr];
  const float bias1 = dense_b[c0base + 16 + lr];

  const int grow   = tid >> 5;
  const int gchunk = tid & 31;
  const int gswz   = grow * HID + ((gchunk ^ (grow & 7)) << 3);
  const int gid_base = (r0 + grow) * T_LEN;

  __syncthreads();

  int cur = 0;
  for (int t = 0; t < T_LEN; ++t) {
    {
      int rid = ids[gid_base + t];
      const f32x4* src = reinterpret_cast<const f32x4*>(emb + (size_t)rid * HID + gchunk * 8);
      f32x4 v0 = src[0];
      f32x4 v1 = src[1];
      uint4 pk;
      pk.x = (unsigned int)f2bf(v0[0]) | ((unsigned int)f2bf(v0[1]) << 16);
      pk.y = (unsigned int)f2bf(v0[2]) | ((unsigned int)f2bf(v0[3]) << 16);
      pk.z = (unsigned int)f2bf(v1[0]) | ((unsigned int)f2bf(v1[1]) << 16);
      pk.w = (unsigned int)f2bf(v1[2]) | ((unsigned int)f2bf(v1[3]) << 16);
      *reinterpret_cast<uint4*>(&x_bf[gswz]) = pk;
    }
    __syncthreads();

    bf16x8 ax[8], ah[8];
    #pragma unroll
    for (int k = 0; k < 8; ++k) {
      ax[k] = lds_frag(x_bf,     lr, k, lq);
      ah[k] = lds_frag(h0b[cur], lr, k, lq);
    }
    layer_step(ax, ah, Wih0, Whh0, hreg0, h0b[cur ^ 1], c0base, lr, lq);
    __syncthreads();

    #pragma unroll
    for (int k = 0; k < 8; ++k) {
      ax[k] = lds_frag(h0b[cur ^ 1], lr, k, lq);
      ah[k] = lds_frag(h1b[cur],     lr, k, lq);
    }
    layer_step(ax, ah, Wih1, Whh1, hreg1, h1b[cur ^ 1], c0base, lr, lq);
    __syncthreads();

    #pragma unroll
    for (int k = 0; k < 8; ++k) ax[k] = lds_frag(h1b[cur ^ 1], lr, k, lq);
    #pragma unroll
    for (int j = 0; j < 2; ++j) {
      const int c0 = c0base + j * 16;
      f32x4 acc = {0,0,0,0};
      #pragma unroll
      for (int k = 0; k < 8; ++k) {
        bf16x8 bw = gw_frag(Wd, c0 + lr, k * 32 + lq * 8);
        acc = __builtin_amdgcn_mfma_f32_16x16x32_bf16(ax[k], bw, acc, 0, 0, 0);
      }
      const float bias = j ? bias1 : bias0;
      size_t base = ((size_t)(r0 + lq * 4) * T_LEN + t) * HID + c0 + lr;
      #pragma unroll
      for (int q = 0; q < 4; ++q) {
        out[base + (size_t)q * T_LEN * HID] = acc[q] + bias;
      }
    }
    cur ^= 1;
  }
}

extern "C" void kernel_launch(void* const* d_in, const int* in_sizes, int n_in,
                              void* d_out, int out_size, void* d_ws, size_t ws_size,
                              hipStream_t stream) {
  const int*   ids  = (const int*)d_in[0];
  const float* emb  = (const float*)d_in[1];
  const float* wih0 = (const float*)d_in[2];
  const float* whh0 = (const float*)d_in[3];
  const float* wih1 = (const float*)d_in[4];
  const float* whh1 = (const float*)d_in[5];
  const float* dw   = (const float*)d_in[6];
  const float* db   = (const float*)d_in[7];

  unsigned short* wbf = (unsigned short*)d_ws;   // 851968 bf16 = 1.7 MB

  const int total = 4 * WSZ + HID * HID;
  convert_weights<<<(total + 255) / 256, 256, 0, stream>>>(wih0, whh0, wih1, whh1, dw, wbf);

  const size_t XP_OFF = 2u * 1024u * 1024u;
  const size_t XP_BYTES = (size_t)T_LEN * G3 * BATCH * 2;        // 314,572,800
  const size_t H_OFF  = XP_OFF + XP_BYTES;
  const size_t H_BYTES = (size_t)BATCH * T_LEN * HID * 2;        // 104,857,600
  const size_t NEED = H_OFF + H_BYTES;                           // ~421.5 MB

  if (ws_size >= NEED) {
    unsigned short* xpT  = (unsigned short*)((char*)d_ws + XP_OFF);
    unsigned short* hbuf = (unsigned short*)((char*)d_ws + H_OFF);
    const unsigned short* Wih0 = wbf;
    const unsigned short* Whh0 = wbf + 1 * WSZ;
    const unsigned short* Wih1 = wbf + 2 * WSZ;
    const unsigned short* Whh1 = wbf + 3 * WSZ;
    const unsigned short* Wd   = wbf + 4 * WSZ;

    xp_gemm<1><<<1600, NTHREADS, 0, stream>>>(ids, emb, nullptr, Wih0, xpT);
    gru_rec<<<64, NTHREADS, 0, stream>>>(xpT, Whh0, hbuf);
    xp_gemm<0><<<1600, NTHREADS, 0, stream>>>(nullptr, nullptr, hbuf, Wih1, xpT);
    gru_rec<<<64, NTHREADS, 0, stream>>>(xpT, Whh1, hbuf);
    dense_gemm<<<1600, NTHREADS, 0, stream>>>(hbuf, Wd, db, (float*)d_out);
  } else {
    gru_fused<<<64, NTHREADS, 0, stream>>>(ids, emb, wbf, db, (float*)d_out);
  }
}